// Round 3
// baseline (834.756 us; speedup 1.0000x reference)
//
#include <hip/hip_runtime.h>
#include <hip/hip_bf16.h>

#define HWD 188
#define NPX (HWD*HWD)
#define NB 4
#define CIN 512
#define CH 64
#define MBOX 200
#define NMAX 500

// output offsets (floats)
#define HEAD_SZ (NB*12*NPX)
#define HM_OFF  HEAD_SZ
#define TB_OFF  (HM_OFF + NB*3*NPX)
#define IND_OFF (TB_OFF + NB*NMAX*8)
#define MSK_OFF (IND_OFF + NB*NMAX)

// LDS pixel stride (shorts): 40 (=80B) -> bank base (20*pix+4*kg)%32, 2-way max
#define PXS 40

typedef short sh8 __attribute__((ext_vector_type(8)));
typedef float f4 __attribute__((ext_vector_type(4)));
typedef unsigned short us4 __attribute__((ext_vector_type(4)));

__device__ __constant__ int d_cum[6]  = {0, 2, 3, 6, 8, 9};
__device__ __constant__ int d_outc[6] = {2, 1, 3, 2, 1, 3};

__device__ __forceinline__ unsigned short bf16_bits(float v) {
  union { __hip_bfloat16 h; unsigned short u; } cv;
  cv.h = __float2bfloat16(v);
  return cv.u;
}

// ---------------- weight pre-transform to bf16 MFMA layouts ----------------
// w1b [9tap][16icq][64oc][32icr] <- w_shared [64][512][3][3]   (contig A-bursts)
// w2b [6][9][64][64] <- w1_heads [6][64][64][3][3]
// w3b [6][9][16][64] <- w2_heads [6][3][64][3][3]  (oc padded 3->16 with 0)
__global__ __launch_bounds__(256) void wprep(
    const float* __restrict__ ws_, const float* __restrict__ w1_,
    const float* __restrict__ w2_, unsigned short* __restrict__ w1b,
    unsigned short* __restrict__ w2b, unsigned short* __restrict__ w3b) {
  int e = blockIdx.x * 256 + threadIdx.x;
  const int N1 = 9 * 16 * 64 * 32;  // 294912
  const int N2 = 6 * 9 * 64 * 64;   // 221184
  const int N3 = 6 * 9 * 16 * 64;   // 55296
  if (e < N1) {
    int icr = e & 31; int r1 = e >> 5;
    int oc = r1 & 63; int r2 = r1 >> 6;
    int icq = r2 & 15; int tap = r2 >> 4;
    w1b[e] = bf16_bits(ws_[(oc * 512 + icq * 32 + icr) * 9 + tap]);
  } else if (e < N1 + N2) {
    int f = e - N1;
    int h = f / (9 * 64 * 64); int r = f % (9 * 64 * 64);
    int tap = r / (64 * 64); int r2 = r % (64 * 64);
    int oc = r2 / 64; int ic = r2 % 64;
    w2b[f] = bf16_bits(w1_[((h * 64 + oc) * 64 + ic) * 9 + tap]);
  } else if (e < N1 + N2 + N3) {
    int f = e - N1 - N2;
    int h = f / (9 * 16 * 64); int r = f % (9 * 16 * 64);
    int tap = r / (16 * 64); int r2 = r % (16 * 64);
    int oc = r2 / 64; int ic = r2 % 64;
    float v = (oc < 3) ? w2_[((h * 3 + oc) * 64 + ic) * 9 + tap] : 0.f;
    w3b[f] = bf16_bits(v);
  }
}

// ---------------- zero f32 accumulator ----------------
__global__ __launch_bounds__(256) void zeroacc(f4* __restrict__ p, int n4) {
  int i = blockIdx.x * 256 + threadIdx.x;
  if (i < n4) p[i] = (f4){0.f, 0.f, 0.f, 0.f};
}

// ---------------- conv1: 512->64 MFMA ----------------
// SPLIT=1: blockIdx.z picks 128-ic chunk, f32 atomicAdd epilogue (grid 2304).
// SPLIT=0: full K, fused BN+ReLU+bf16 epilogue (grid 576, ws-small fallback).
template<int SPLIT>
__global__ __launch_bounds__(256) void conv1_mfma(
    const float* __restrict__ sf,           // [B][512][188][188] f32
    const unsigned short* __restrict__ wb,  // [9][16][64][32] bf16
    const float* __restrict__ bnp,          // [4][64] (SPLIT=0)
    float* __restrict__ accf,               // NHWC f32 (SPLIT=1)
    unsigned short* __restrict__ outp) {    // NHWC bf16 (SPLIT=0)
  __shared__ __align__(16) short s_in[10 * 34 * PXS];
  const int t = threadIdx.x;
  const int b = blockIdx.y;
  const int ks = SPLIT ? blockIdx.z : 0;
  const int rt = blockIdx.x / 6, ct = blockIdx.x % 6;
  const int y0 = rt * 8, x0 = ct * 32;
  const int w = t >> 6, lane = t & 63, ln = lane & 15, kg = lane >> 4;

  f4 acc[4][4];
#pragma unroll
  for (int i = 0; i < 4; ++i)
#pragma unroll
    for (int j = 0; j < 4; ++j) acc[i][j] = (f4){0.f, 0.f, 0.f, 0.f};

  const int NSTEP = SPLIT ? 4 : 16;
  for (int s = 0; s < NSTEP; ++s) {
    const int icq = ks * 4 + s;          // global 32-ic chunk index
    const int ic0 = icq * 32;
    __syncthreads();
    for (int idx = t; idx < 2720; idx += 256) {
      int c = idx % 34; int rem = idx / 34;
      int r = rem % 10; int iq = rem / 10;
      int gy = y0 - 1 + r, gx = x0 - 1 + c;
      float v0 = 0.f, v1 = 0.f, v2 = 0.f, v3 = 0.f;
      if (gy >= 0 && gy < HWD && gx >= 0 && gx < HWD) {
        const float* p = sf + ((b * CIN + ic0 + iq * 4) * HWD + gy) * HWD + gx;
        v0 = p[0]; v1 = p[NPX]; v2 = p[2 * NPX]; v3 = p[3 * NPX];
      }
      us4 pk = {bf16_bits(v0), bf16_bits(v1), bf16_bits(v2), bf16_bits(v3)};
      *reinterpret_cast<us4*>(&s_in[(r * 34 + c) * PXS + iq * 4]) = pk;
    }
    __syncthreads();
    for (int tap = 0; tap < 9; ++tap) {
      const int ky = tap / 3, kx = tap % 3;
      sh8 af[4];
#pragma unroll
      for (int ot = 0; ot < 4; ++ot)
        af[ot] = *reinterpret_cast<const sh8*>(
            wb + (((tap * 16 + icq) * 64) + ot * 16 + ln) * 32 + kg * 8);
#pragma unroll
      for (int nt = 0; nt < 4; ++nt) {
        const int rr = 2 * w + (nt >> 1) + ky;
        const int cc = (nt & 1) * 16 + ln + kx;
        sh8 bf = *reinterpret_cast<const sh8*>(&s_in[(rr * 34 + cc) * PXS + kg * 8]);
#pragma unroll
        for (int ot = 0; ot < 4; ++ot)
          acc[ot][nt] = __builtin_amdgcn_mfma_f32_16x16x32_bf16(
              af[ot], bf, acc[ot][nt], 0, 0, 0);
      }
    }
  }
  if (SPLIT) {
#pragma unroll
    for (int ot = 0; ot < 4; ++ot) {
#pragma unroll
      for (int nt = 0; nt < 4; ++nt) {
        int y = y0 + 2 * w + (nt >> 1);
        int x = x0 + (nt & 1) * 16 + ln;
        if (y < HWD && x < HWD) {
          float* p = accf + ((b * HWD + y) * HWD + x) * 64 + ot * 16 + kg * 4;
#pragma unroll
          for (int j = 0; j < 4; ++j) atomicAdd(p + j, acc[ot][nt][j]);
        }
      }
    }
  } else {
#pragma unroll
    for (int ot = 0; ot < 4; ++ot) {
      const int ocb = ot * 16 + kg * 4;
      f4 g4 = *reinterpret_cast<const f4*>(bnp + ocb);
      f4 b4 = *reinterpret_cast<const f4*>(bnp + 64 + ocb);
      f4 m4 = *reinterpret_cast<const f4*>(bnp + 128 + ocb);
      f4 v4 = *reinterpret_cast<const f4*>(bnp + 192 + ocb);
      f4 sc, bi;
#pragma unroll
      for (int j = 0; j < 4; ++j) {
        sc[j] = g4[j] * rsqrtf(v4[j] + 1e-5f);
        bi[j] = b4[j] - m4[j] * sc[j];
      }
#pragma unroll
      for (int nt = 0; nt < 4; ++nt) {
        int y = y0 + 2 * w + (nt >> 1);
        int x = x0 + (nt & 1) * 16 + ln;
        if (y < HWD && x < HWD) {
          us4 pk;
#pragma unroll
          for (int j = 0; j < 4; ++j)
            pk[j] = bf16_bits(fmaxf(acc[ot][nt][j] * sc[j] + bi[j], 0.f));
          *reinterpret_cast<us4*>(outp + ((b * HWD + y) * HWD + x) * 64 + ocb) = pk;
        }
      }
    }
  }
}

// ---------------- BN+ReLU+pack: accf f32 NHWC -> shared bf16 NHWC ----------------
__global__ __launch_bounds__(256) void bn_pack(
    const float* __restrict__ accf, const float* __restrict__ bnp,
    unsigned short* __restrict__ outp) {
  __shared__ float s_sc[64], s_bi[64];
  const int t = threadIdx.x;
  if (t < 64) {
    float g = bnp[t], be = bnp[64 + t], m = bnp[128 + t], v = bnp[192 + t];
    float sc = g * rsqrtf(v + 1e-5f);
    s_sc[t] = sc; s_bi[t] = be - m * sc;
  }
  __syncthreads();
  int idx = blockIdx.x * 256 + t;           // over NB*NPX*4
  if (idx >= NB * NPX * 4) return;
  int px = idx >> 2, q = idx & 3;
  const float* p = accf + (long long)px * 64 + q * 16;
  unsigned short* o = outp + (long long)px * 64 + q * 16;
  const int ocb = q * 16;
#pragma unroll
  for (int k = 0; k < 4; ++k) {
    f4 v4 = *reinterpret_cast<const f4*>(p + k * 4);
    us4 pk;
#pragma unroll
    for (int j = 0; j < 4; ++j)
      pk[j] = bf16_bits(fmaxf(v4[j] * s_sc[ocb + k * 4 + j] + s_bi[ocb + k * 4 + j], 0.f));
    *reinterpret_cast<us4*>(o + k * 4) = pk;
  }
}

// ---------------- head convs (64->64 BN+ReLU | 64->16(3) +bias) ----------------
template<int OCT, int EPI>
__global__ __launch_bounds__(256) void conv_head_mfma(
    const unsigned short* __restrict__ inp,   // NHWC bf16 (EPI1: tmp base)
    const unsigned short* __restrict__ wb0,   // [6][9][OCT*16][64]
    const float* __restrict__ bn0,            // EPI0: [6][4][64]
    const float* __restrict__ b2,             // EPI1: [6][3]
    unsigned short* __restrict__ outp0,       // EPI0: tmp base
    float* __restrict__ hout,                 // EPI1: head_out
    int h_base, long long stride) {
  __shared__ __align__(16) short s_in[10 * 34 * PXS];
  const int t = threadIdx.x;
  const int b = blockIdx.y;
  const int h = h_base + blockIdx.z;
  const int rt = blockIdx.x / 6, ct = blockIdx.x % 6;
  const int y0 = rt * 8, x0 = ct * 32;
  const int w = t >> 6, lane = t & 63, ln = lane & 15, kg = lane >> 4;

  const unsigned short* wb = wb0 + h * (9 * OCT * 16 * 64);
  const unsigned short* in_t = (EPI == 1) ? inp + h * stride : inp;

  f4 acc[OCT][4];
#pragma unroll
  for (int i = 0; i < OCT; ++i)
#pragma unroll
    for (int j = 0; j < 4; ++j) acc[i][j] = (f4){0.f, 0.f, 0.f, 0.f};

  for (int ic0 = 0; ic0 < CH; ic0 += 32) {
    __syncthreads();
    for (int idx = t; idx < 1360; idx += 256) {
      int icg = idx & 3; int pix = idx >> 2;
      int c = pix % 34; int r = pix / 34;
      int gy = y0 - 1 + r, gx = x0 - 1 + c;
      sh8 v = (sh8){0, 0, 0, 0, 0, 0, 0, 0};
      if (gy >= 0 && gy < HWD && gx >= 0 && gx < HWD)
        v = *reinterpret_cast<const sh8*>(
            &in_t[((b * HWD + gy) * HWD + gx) * 64 + ic0 + icg * 8]);
      *reinterpret_cast<sh8*>(&s_in[(r * 34 + c) * PXS + icg * 8]) = v;
    }
    __syncthreads();
    for (int tap = 0; tap < 9; ++tap) {
      const int ky = tap / 3, kx = tap % 3;
      sh8 af[OCT];
#pragma unroll
      for (int ot = 0; ot < OCT; ++ot)
        af[ot] = *reinterpret_cast<const sh8*>(
            wb + (tap * OCT * 16 + ot * 16 + ln) * 64 + ic0 + kg * 8);
#pragma unroll
      for (int nt = 0; nt < 4; ++nt) {
        const int rr = 2 * w + (nt >> 1) + ky;
        const int cc = (nt & 1) * 16 + ln + kx;
        sh8 bf = *reinterpret_cast<const sh8*>(&s_in[(rr * 34 + cc) * PXS + kg * 8]);
#pragma unroll
        for (int ot = 0; ot < OCT; ++ot)
          acc[ot][nt] = __builtin_amdgcn_mfma_f32_16x16x32_bf16(
              af[ot], bf, acc[ot][nt], 0, 0, 0);
      }
    }
  }
  if (EPI == 0) {
    unsigned short* outp = outp0 + h * stride;
#pragma unroll
    for (int ot = 0; ot < OCT; ++ot) {
      const int ocb = ot * 16 + kg * 4;
      const float* bnp = bn0 + h * 256;
      f4 g4 = *reinterpret_cast<const f4*>(bnp + ocb);
      f4 b4 = *reinterpret_cast<const f4*>(bnp + 64 + ocb);
      f4 m4 = *reinterpret_cast<const f4*>(bnp + 128 + ocb);
      f4 v4 = *reinterpret_cast<const f4*>(bnp + 192 + ocb);
      f4 sc, bi;
#pragma unroll
      for (int j = 0; j < 4; ++j) {
        sc[j] = g4[j] * rsqrtf(v4[j] + 1e-5f);
        bi[j] = b4[j] - m4[j] * sc[j];
      }
#pragma unroll
      for (int nt = 0; nt < 4; ++nt) {
        int y = y0 + 2 * w + (nt >> 1);
        int x = x0 + (nt & 1) * 16 + ln;
        if (y < HWD && x < HWD) {
          us4 pk;
#pragma unroll
          for (int j = 0; j < 4; ++j)
            pk[j] = bf16_bits(fmaxf(acc[ot][nt][j] * sc[j] + bi[j], 0.f));
          *reinterpret_cast<us4*>(outp + ((b * HWD + y) * HWD + x) * 64 + ocb) = pk;
        }
      }
    }
  } else {
    const int c_off = d_cum[h], noc = d_outc[h];
    const float* bias = b2 + h * 3;
#pragma unroll
    for (int nt = 0; nt < 4; ++nt) {
      int y = y0 + 2 * w + (nt >> 1);
      int x = x0 + (nt & 1) * 16 + ln;
      if (y < HWD && x < HWD) {
#pragma unroll
        for (int j = 0; j < 4; ++j) {
          int oc = kg * 4 + j;
          if (oc < noc)
            hout[(b * 12 + c_off + oc) * NPX + y * HWD + x] =
                acc[0][nt][j] + bias[oc];
        }
      }
    }
  }
}

// ---------------- assign_targets: per-box ----------------
__global__ __launch_bounds__(256) void targets_kernel(
    const float* __restrict__ gt, float* __restrict__ out, float* __restrict__ boxp) {
  int idx = blockIdx.x * 256 + threadIdx.x;
  if (idx >= NB * NMAX) return;
  int b = idx / NMAX, j = idx - b * NMAX;
  float vals[8] = {0, 0, 0, 0, 0, 0, 0, 0};
  float indf = 0.f, mkf = 0.f;
  if (j < MBOX) {
    const float* g = gt + (b * MBOX + j) * 8;
    float x = g[0], y = g[1], z = g[2], dx = g[3], dy = g[4], dz = g[5];
    float hd = g[6], cls = g[7];
    float cx = (x - (-75.2f)) / 0.1f / 8.0f;
    cx = fminf(fmaxf(cx, 0.0f), (float)HWD - 0.5f);
    float cy = (y - (-75.2f)) / 0.1f / 8.0f;
    cy = fminf(fmaxf(cy, 0.0f), (float)HWD - 0.5f);
    float cxf = floorf(cx), cyf = floorf(cy);
    int cxi = (int)cxf, cyi = (int)cyf;
    float hh = dx / 0.1f / 8.0f;
    float ww = dy / 0.1f / 8.0f;
    const float ov = 0.1f;
    float b1 = hh + ww;
    float c1 = ww * hh * (1.0f - ov) / (1.0f + ov);
    float sq1 = sqrtf(fmaxf(b1 * b1 - 4.0f * c1, 0.0f));
    float r1 = (b1 + sq1) / 2.0f;
    float b2_ = 2.0f * (hh + ww);
    float c2 = (1.0f - ov) * ww * hh;
    float sq2 = sqrtf(fmaxf(b2_ * b2_ - 16.0f * c2, 0.0f));
    float r2 = (b2_ + sq2) / 2.0f;
    float a3 = 4.0f * ov;
    float b3 = -2.0f * ov * (hh + ww);
    float c3 = (ov - 1.0f) * ww * hh;
    float sq3 = sqrtf(fmaxf(b3 * b3 - 4.0f * a3 * c3, 0.0f));
    float r3 = (b3 + sq3) / 2.0f;
    float r = fminf(fminf(r1, r2), r3);
    r = fmaxf(floorf(r), 2.0f);
    float sigma = (2.0f * r + 1.0f) / 6.0f;
    float inv2s2 = 1.0f / (2.0f * sigma * sigma);
    bool valid = (dx > 0.0f) && (dy > 0.0f);
    float vf = valid ? 1.0f : 0.0f;
    vals[0] = (cx - cxf) * vf;
    vals[1] = (cy - cyf) * vf;
    vals[2] = z * vf;
    vals[3] = logf(dx) * vf;
    vals[4] = logf(dy) * vf;
    vals[5] = logf(dz) * vf;
    vals[6] = cosf(hd) * vf;
    vals[7] = sinf(hd) * vf;
    indf = (float)((cyi * HWD + cxi) * (valid ? 1 : 0));
    mkf = vf;
    float* bp = boxp + (b * MBOX + j) * 8;
    bp[0] = cxf; bp[1] = cyf; bp[2] = r; bp[3] = inv2s2;
    bp[4] = valid ? cls : 0.0f; bp[5] = 0.f; bp[6] = 0.f; bp[7] = 0.f;
  }
  float* tb = out + TB_OFF + (b * NMAX + j) * 8;
#pragma unroll
  for (int k = 0; k < 8; ++k) tb[k] = vals[k];
  out[IND_OFF + b * NMAX + j] = indf;
  out[MSK_OFF + b * NMAX + j] = mkf;
}

// ---------------- heatmap: per-pixel max over boxes ----------------
__global__ __launch_bounds__(256) void heatmap_kernel(
    const float* __restrict__ boxp, float* __restrict__ out) {
  __shared__ float s_bp[MBOX][5];
  const int t = threadIdx.x, b = blockIdx.y;
  for (int e = t; e < MBOX * 5; e += 256) {
    int j = e / 5, k = e - j * 5;
    s_bp[j][k] = boxp[(b * MBOX + j) * 8 + k];
  }
  __syncthreads();
  int p = blockIdx.x * 256 + t;
  if (p >= NPX) return;
  int y = p / HWD, x = p - y * HWD;
  float a0 = 0.f, a1 = 0.f, a2 = 0.f;
  for (int j = 0; j < MBOX; ++j) {
    int c = (int)s_bp[j][4];
    if (c == 0) continue;
    float ox = (float)x - s_bp[j][0];
    float oy = (float)y - s_bp[j][1];
    float r = s_bp[j][2];
    if (fabsf(ox) <= r && fabsf(oy) <= r) {
      float gg = expf(-(ox * ox + oy * oy) * s_bp[j][3]);
      if (c == 1) a0 = fmaxf(a0, gg);
      else if (c == 2) a1 = fmaxf(a1, gg);
      else a2 = fmaxf(a2, gg);
    }
  }
  int base = HM_OFF + (b * 3 * HWD + y) * HWD + x;
  out[base] = a0;
  out[base + NPX] = a1;
  out[base + 2 * NPX] = a2;
}

extern "C" void kernel_launch(void* const* d_in, const int* in_sizes, int n_in,
                              void* d_out, int out_size, void* d_ws, size_t ws_size,
                              hipStream_t stream) {
  (void)in_sizes; (void)n_in; (void)out_size;
  const float* sf = (const float*)d_in[0];
  const float* gt = (const float*)d_in[1];
  const float* w_shared = (const float*)d_in[2];
  const float* bn_shared = (const float*)d_in[3];
  const float* w1 = (const float*)d_in[4];
  const float* bnH = (const float*)d_in[5];
  const float* w2 = (const float*)d_in[6];
  const float* b2 = (const float*)d_in[7];
  float* out = (float*)d_out;
  char* ws = (char*)d_ws;

  // ws layout (bytes)
  const size_t SH = (size_t)NB * NPX * 64 * 2;          // 18,096,128
  unsigned short* shared_t = (unsigned short*)ws;
  unsigned short* w1b = (unsigned short*)(ws + SH);                       // 589,824
  unsigned short* w2b = (unsigned short*)(ws + SH + 589824);              // 442,368
  unsigned short* w3b = (unsigned short*)(ws + SH + 589824 + 442368);     // 110,592
  float* boxp = (float*)(ws + SH + 589824 + 442368 + 110592);             // 25,600
  const size_t off_acc = SH + 589824 + 442368 + 110592 + 25600;           // 19,264,512
  float* accf = (float*)(ws + off_acc);                 // 36,192,256 (aliases tmp)
  unsigned short* tmp0 = (unsigned short*)(ws + off_acc);

  const size_t ACC_B = (size_t)NB * NPX * 64 * 4;
  const bool split = ws_size >= off_acc + ACC_B;                 // 55.5 MB
  const bool wide = ws_size >= off_acc + 6 * SH;                 // 127.9 MB
  const long long tstride = wide ? (long long)(SH / 2) : 0LL;    // shorts

  wprep<<<2232, 256, 0, stream>>>(w_shared, w1, w2, w1b, w2b, w3b);

  if (split) {
    const int n4 = NB * NPX * 16;  // f4 count = NB*NPX*64/4
    zeroacc<<<(n4 + 255) / 256, 256, 0, stream>>>((f4*)accf, n4);
    conv1_mfma<1><<<dim3(144, NB, 4), 256, 0, stream>>>(
        sf, w1b, nullptr, accf, nullptr);
    bn_pack<<<(NB * NPX * 4 + 255) / 256, 256, 0, stream>>>(
        accf, bn_shared, shared_t);
  } else {
    conv1_mfma<0><<<dim3(144, NB), 256, 0, stream>>>(
        sf, w1b, bn_shared, nullptr, shared_t);
  }

  if (wide) {
    conv_head_mfma<4, 0><<<dim3(144, NB, 6), 256, 0, stream>>>(
        shared_t, w2b, bnH, nullptr, tmp0, nullptr, 0, tstride);
    conv_head_mfma<1, 1><<<dim3(144, NB, 6), 256, 0, stream>>>(
        tmp0, w3b, nullptr, b2, nullptr, out, 0, tstride);
  } else {
    for (int h = 0; h < 6; ++h) {
      conv_head_mfma<4, 0><<<dim3(144, NB), 256, 0, stream>>>(
          shared_t, w2b, bnH, nullptr, tmp0, nullptr, h, 0);
      conv_head_mfma<1, 1><<<dim3(144, NB), 256, 0, stream>>>(
          tmp0, w3b, nullptr, b2, nullptr, out, h, 0);
    }
  }

  targets_kernel<<<(NB * NMAX + 255) / 256, 256, 0, stream>>>(gt, out, boxp);
  heatmap_kernel<<<dim3((NPX + 255) / 256, NB), 256, 0, stream>>>(boxp, out);
}

// Round 4
// 553.567 us; speedup vs baseline: 1.5080x; 1.5080x over previous
//
#include <hip/hip_runtime.h>
#include <hip/hip_bf16.h>

#define HWD 188
#define NPX (HWD*HWD)
#define NB 4
#define CIN 512
#define CH 64
#define MBOX 200
#define NMAX 500

// output offsets (floats)
#define HEAD_SZ (NB*12*NPX)
#define HM_OFF  HEAD_SZ
#define TB_OFF  (HM_OFF + NB*3*NPX)
#define IND_OFF (TB_OFF + NB*NMAX*8)
#define MSK_OFF (IND_OFF + NB*NMAX)

// LDS pixel stride (shorts): 40 (=80B) -> ds_read_b128 covers all 32 banks per
// 8 lanes (bank base 20*pix+4*kg mod 32), conflict-free by construction.
#define PXS 40

typedef short sh8 __attribute__((ext_vector_type(8)));
typedef float f4 __attribute__((ext_vector_type(4)));
typedef unsigned short us4 __attribute__((ext_vector_type(4)));

__device__ __constant__ int d_cum[6]  = {0, 2, 3, 6, 8, 9};
__device__ __constant__ int d_outc[6] = {2, 1, 3, 2, 1, 3};

__device__ __forceinline__ unsigned short bf16_bits(float v) {
  union { __hip_bfloat16 h; unsigned short u; } cv;
  cv.h = __float2bfloat16(v);
  return cv.u;
}

// ---------------- weight pre-transform to bf16 MFMA layouts ----------------
// w1b [9tap][16icq][64oc][32icr] <- w_shared [64][512][3][3]   (contig A-bursts)
// w2b [6][9][64][64] <- w1_heads [6][64][64][3][3]
// w3b [6][9][16][64] <- w2_heads [6][3][64][3][3]  (oc padded 3->16 with 0)
__global__ __launch_bounds__(256) void wprep(
    const float* __restrict__ ws_, const float* __restrict__ w1_,
    const float* __restrict__ w2_, unsigned short* __restrict__ w1b,
    unsigned short* __restrict__ w2b, unsigned short* __restrict__ w3b) {
  int e = blockIdx.x * 256 + threadIdx.x;
  const int N1 = 9 * 16 * 64 * 32;  // 294912
  const int N2 = 6 * 9 * 64 * 64;   // 221184
  const int N3 = 6 * 9 * 16 * 64;   // 55296
  if (e < N1) {
    int icr = e & 31; int r1 = e >> 5;
    int oc = r1 & 63; int r2 = r1 >> 6;
    int icq = r2 & 15; int tap = r2 >> 4;
    w1b[e] = bf16_bits(ws_[(oc * 512 + icq * 32 + icr) * 9 + tap]);
  } else if (e < N1 + N2) {
    int f = e - N1;
    int h = f / (9 * 64 * 64); int r = f % (9 * 64 * 64);
    int tap = r / (64 * 64); int r2 = r % (64 * 64);
    int oc = r2 / 64; int ic = r2 % 64;
    w2b[f] = bf16_bits(w1_[((h * 64 + oc) * 64 + ic) * 9 + tap]);
  } else if (e < N1 + N2 + N3) {
    int f = e - N1 - N2;
    int h = f / (9 * 16 * 64); int r = f % (9 * 16 * 64);
    int tap = r / (16 * 64); int r2 = r % (16 * 64);
    int oc = r2 / 64; int ic = r2 % 64;
    float v = (oc < 3) ? w2_[((h * 3 + oc) * 64 + ic) * 9 + tap] : 0.f;
    w3b[f] = bf16_bits(v);
  }
}

// ---------- conv1 staging helpers (item = (r*10+cc)*8 + icg, 800 items) ----------
// Each item: 4 aligned float4 loads (4 ic planes, 4 consecutive x), later stored
// as 4 us4 LDS writes (consecutive lanes -> icg fastest -> 8B apart, 2-way free).
__device__ __forceinline__ void stage_load(
    const float* __restrict__ sf, int b, int ic0, int y0, int x0, int item,
    f4 v[4]) {
#pragma unroll
  for (int j = 0; j < 4; ++j) v[j] = (f4){0.f, 0.f, 0.f, 0.f};
  int icg = item & 7; int pc = item >> 3;
  int cc = pc % 10; int r = pc / 10;
  int gy = y0 - 1 + r;
  int gx0 = x0 - 4 + cc * 4;
  if (gy >= 0 && gy < HWD) {
    const float* p = sf + (((long long)b * CIN + ic0 + icg * 4) * HWD + gy) * HWD + gx0;
    if (gx0 >= 0 && gx0 + 3 < HWD) {
#pragma unroll
      for (int j = 0; j < 4; ++j) v[j] = *reinterpret_cast<const f4*>(p + j * NPX);
    } else {
#pragma unroll
      for (int k = 0; k < 4; ++k) {
        int gx = gx0 + k;
        if (gx >= 0 && gx < HWD) {
#pragma unroll
          for (int j = 0; j < 4; ++j) v[j][k] = p[j * NPX + k];
        }
      }
    }
  }
}

__device__ __forceinline__ void stage_write(short* buf, int item, const f4 v[4]) {
  int icg = item & 7; int pc = item >> 3;
  int cc = pc % 10; int r = pc / 10;
#pragma unroll
  for (int k = 0; k < 4; ++k) {
    int col = cc * 4 + k - 3;
    if (col >= 0 && col < 34) {
      us4 pk = {bf16_bits(v[0][k]), bf16_bits(v[1][k]),
                bf16_bits(v[2][k]), bf16_bits(v[3][k])};
      *reinterpret_cast<us4*>(&buf[(r * 34 + col) * PXS + icg * 4]) = pk;
    }
  }
}

// ---------------- conv1: 512->64 MFMA, fused BN+ReLU -> bf16 NHWC ----------------
// 512 threads = 8 waves. tile 8r x 32c x 64oc. wave (rp = w&3, oh = w>>2):
// rows 2rp..2rp+1, oc-tiles {2oh, 2oh+1}. Double-buffered LDS; T14 split:
// issue next-step loads -> MFMA phase -> LDS write -> barrier.
__global__ __launch_bounds__(512, 4) void conv1_mfma(
    const float* __restrict__ sf,           // [B][512][188][188] f32
    const unsigned short* __restrict__ wb,  // [9][16][64][32] bf16
    const float* __restrict__ bnp,          // [4][64]
    unsigned short* __restrict__ outp) {    // NHWC [B][188][188][64] bf16
  __shared__ __align__(16) short s_in[2][10 * 34 * PXS];
  const int t = threadIdx.x;
  const int b = blockIdx.y;
  const int rt = blockIdx.x / 6, ct = blockIdx.x % 6;
  const int y0 = rt * 8, x0 = ct * 32;
  const int w = t >> 6, lane = t & 63, ln = lane & 15, kg = lane >> 4;
  const int rp = w & 3, oh = w >> 2;

  f4 acc[2][4];
#pragma unroll
  for (int i = 0; i < 2; ++i)
#pragma unroll
    for (int j = 0; j < 4; ++j) acc[i][j] = (f4){0.f, 0.f, 0.f, 0.f};

  const bool has2 = (t < 800 - 512);
  f4 st0[4], st1[4];

  // prologue: stage step 0 into buf 0
  stage_load(sf, b, 0, y0, x0, t, st0);
  if (has2) stage_load(sf, b, 0, y0, x0, t + 512, st1);
  stage_write(s_in[0], t, st0);
  if (has2) stage_write(s_in[0], t + 512, st1);
  __syncthreads();

  for (int s = 0; s < 16; ++s) {
    const short* cur = s_in[s & 1];
    // phase A: issue global loads for step s+1 (in flight through phase B)
    if (s < 15) {
      stage_load(sf, b, (s + 1) * 32, y0, x0, t, st0);
      if (has2) stage_load(sf, b, (s + 1) * 32, y0, x0, t + 512, st1);
    }
    // phase B: 9 taps x (2 A-frags, 4 B-frags, 8 MFMA)
    const int icq = s;
#pragma unroll
    for (int tap = 0; tap < 9; ++tap) {
      const int ky = tap / 3, kx = tap % 3;
      sh8 af[2];
#pragma unroll
      for (int i = 0; i < 2; ++i)
        af[i] = *reinterpret_cast<const sh8*>(
            wb + (((tap * 16 + icq) * 64) + (2 * oh + i) * 16 + ln) * 32 + kg * 8);
#pragma unroll
      for (int nt = 0; nt < 4; ++nt) {
        const int rr = 2 * rp + (nt >> 1) + ky;
        const int cc = (nt & 1) * 16 + ln + kx;
        sh8 bf = *reinterpret_cast<const sh8*>(&cur[(rr * 34 + cc) * PXS + kg * 8]);
#pragma unroll
        for (int i = 0; i < 2; ++i)
          acc[i][nt] = __builtin_amdgcn_mfma_f32_16x16x32_bf16(
              af[i], bf, acc[i][nt], 0, 0, 0);
      }
    }
    // phase C: drain loads, write next buffer
    if (s < 15) {
      short* nxt = s_in[(s & 1) ^ 1];
      stage_write(nxt, t, st0);
      if (has2) stage_write(nxt, t + 512, st1);
    }
    __syncthreads();
  }

  // epilogue: BN + ReLU -> bf16 NHWC
#pragma unroll
  for (int i = 0; i < 2; ++i) {
    const int ocb = (2 * oh + i) * 16 + kg * 4;
    f4 g4 = *reinterpret_cast<const f4*>(bnp + ocb);
    f4 b4 = *reinterpret_cast<const f4*>(bnp + 64 + ocb);
    f4 m4 = *reinterpret_cast<const f4*>(bnp + 128 + ocb);
    f4 v4 = *reinterpret_cast<const f4*>(bnp + 192 + ocb);
    f4 sc, bi;
#pragma unroll
    for (int j = 0; j < 4; ++j) {
      sc[j] = g4[j] * rsqrtf(v4[j] + 1e-5f);
      bi[j] = b4[j] - m4[j] * sc[j];
    }
#pragma unroll
    for (int nt = 0; nt < 4; ++nt) {
      int y = y0 + 2 * rp + (nt >> 1);
      int x = x0 + (nt & 1) * 16 + ln;
      if (y < HWD && x < HWD) {
        us4 pk;
#pragma unroll
        for (int j = 0; j < 4; ++j)
          pk[j] = bf16_bits(fmaxf(acc[i][nt][j] * sc[j] + bi[j], 0.f));
        *reinterpret_cast<us4*>(outp + ((b * HWD + y) * HWD + x) * 64 + ocb) = pk;
      }
    }
  }
}

// ---------------- head convs (64->64 BN+ReLU | 64->16(3) +bias) ----------------
template<int OCT, int EPI>
__global__ __launch_bounds__(256) void conv_head_mfma(
    const unsigned short* __restrict__ inp,   // NHWC bf16 (EPI1: tmp base)
    const unsigned short* __restrict__ wb0,   // [6][9][OCT*16][64]
    const float* __restrict__ bn0,            // EPI0: [6][4][64]
    const float* __restrict__ b2,             // EPI1: [6][3]
    unsigned short* __restrict__ outp0,       // EPI0: tmp base
    float* __restrict__ hout,                 // EPI1: head_out
    int h_base, long long stride) {
  __shared__ __align__(16) short s_in[10 * 34 * PXS];
  const int t = threadIdx.x;
  const int b = blockIdx.y;
  const int h = h_base + blockIdx.z;
  const int rt = blockIdx.x / 6, ct = blockIdx.x % 6;
  const int y0 = rt * 8, x0 = ct * 32;
  const int w = t >> 6, lane = t & 63, ln = lane & 15, kg = lane >> 4;

  const unsigned short* wb = wb0 + h * (9 * OCT * 16 * 64);
  const unsigned short* in_t = (EPI == 1) ? inp + h * stride : inp;

  f4 acc[OCT][4];
#pragma unroll
  for (int i = 0; i < OCT; ++i)
#pragma unroll
    for (int j = 0; j < 4; ++j) acc[i][j] = (f4){0.f, 0.f, 0.f, 0.f};

  for (int ic0 = 0; ic0 < CH; ic0 += 32) {
    __syncthreads();
    for (int idx = t; idx < 1360; idx += 256) {
      int icg = idx & 3; int pix = idx >> 2;
      int c = pix % 34; int r = pix / 34;
      int gy = y0 - 1 + r, gx = x0 - 1 + c;
      sh8 v = (sh8){0, 0, 0, 0, 0, 0, 0, 0};
      if (gy >= 0 && gy < HWD && gx >= 0 && gx < HWD)
        v = *reinterpret_cast<const sh8*>(
            &in_t[((b * HWD + gy) * HWD + gx) * 64 + ic0 + icg * 8]);
      *reinterpret_cast<sh8*>(&s_in[(r * 34 + c) * PXS + icg * 8]) = v;
    }
    __syncthreads();
    for (int tap = 0; tap < 9; ++tap) {
      const int ky = tap / 3, kx = tap % 3;
      sh8 af[OCT];
#pragma unroll
      for (int ot = 0; ot < OCT; ++ot)
        af[ot] = *reinterpret_cast<const sh8*>(
            wb + (tap * OCT * 16 + ot * 16 + ln) * 64 + ic0 + kg * 8);
#pragma unroll
      for (int nt = 0; nt < 4; ++nt) {
        const int rr = 2 * w + (nt >> 1) + ky;
        const int cc = (nt & 1) * 16 + ln + kx;
        sh8 bf = *reinterpret_cast<const sh8*>(&s_in[(rr * 34 + cc) * PXS + kg * 8]);
#pragma unroll
        for (int ot = 0; ot < OCT; ++ot)
          acc[ot][nt] = __builtin_amdgcn_mfma_f32_16x16x32_bf16(
              af[ot], bf, acc[ot][nt], 0, 0, 0);
      }
    }
  }
  if (EPI == 0) {
    unsigned short* outp = outp0 + h * stride;
#pragma unroll
    for (int ot = 0; ot < OCT; ++ot) {
      const int ocb = ot * 16 + kg * 4;
      const float* bnp = bn0 + h * 256;
      f4 g4 = *reinterpret_cast<const f4*>(bnp + ocb);
      f4 b4 = *reinterpret_cast<const f4*>(bnp + 64 + ocb);
      f4 m4 = *reinterpret_cast<const f4*>(bnp + 128 + ocb);
      f4 v4 = *reinterpret_cast<const f4*>(bnp + 192 + ocb);
      f4 sc, bi;
#pragma unroll
      for (int j = 0; j < 4; ++j) {
        sc[j] = g4[j] * rsqrtf(v4[j] + 1e-5f);
        bi[j] = b4[j] - m4[j] * sc[j];
      }
#pragma unroll
      for (int nt = 0; nt < 4; ++nt) {
        int y = y0 + 2 * w + (nt >> 1);
        int x = x0 + (nt & 1) * 16 + ln;
        if (y < HWD && x < HWD) {
          us4 pk;
#pragma unroll
          for (int j = 0; j < 4; ++j)
            pk[j] = bf16_bits(fmaxf(acc[ot][nt][j] * sc[j] + bi[j], 0.f));
          *reinterpret_cast<us4*>(outp + ((b * HWD + y) * HWD + x) * 64 + ocb) = pk;
        }
      }
    }
  } else {
    const int c_off = d_cum[h], noc = d_outc[h];
    const float* bias = b2 + h * 3;
#pragma unroll
    for (int nt = 0; nt < 4; ++nt) {
      int y = y0 + 2 * w + (nt >> 1);
      int x = x0 + (nt & 1) * 16 + ln;
      if (y < HWD && x < HWD) {
#pragma unroll
        for (int j = 0; j < 4; ++j) {
          int oc = kg * 4 + j;
          if (oc < noc)
            hout[(b * 12 + c_off + oc) * NPX + y * HWD + x] =
                acc[0][nt][j] + bias[oc];
        }
      }
    }
  }
}

// ---------------- assign_targets: per-box ----------------
__global__ __launch_bounds__(256) void targets_kernel(
    const float* __restrict__ gt, float* __restrict__ out, float* __restrict__ boxp) {
  int idx = blockIdx.x * 256 + threadIdx.x;
  if (idx >= NB * NMAX) return;
  int b = idx / NMAX, j = idx - b * NMAX;
  float vals[8] = {0, 0, 0, 0, 0, 0, 0, 0};
  float indf = 0.f, mkf = 0.f;
  if (j < MBOX) {
    const float* g = gt + (b * MBOX + j) * 8;
    float x = g[0], y = g[1], z = g[2], dx = g[3], dy = g[4], dz = g[5];
    float hd = g[6], cls = g[7];
    float cx = (x - (-75.2f)) / 0.1f / 8.0f;
    cx = fminf(fmaxf(cx, 0.0f), (float)HWD - 0.5f);
    float cy = (y - (-75.2f)) / 0.1f / 8.0f;
    cy = fminf(fmaxf(cy, 0.0f), (float)HWD - 0.5f);
    float cxf = floorf(cx), cyf = floorf(cy);
    int cxi = (int)cxf, cyi = (int)cyf;
    float hh = dx / 0.1f / 8.0f;
    float ww = dy / 0.1f / 8.0f;
    const float ov = 0.1f;
    float b1 = hh + ww;
    float c1 = ww * hh * (1.0f - ov) / (1.0f + ov);
    float sq1 = sqrtf(fmaxf(b1 * b1 - 4.0f * c1, 0.0f));
    float r1 = (b1 + sq1) / 2.0f;
    float b2_ = 2.0f * (hh + ww);
    float c2 = (1.0f - ov) * ww * hh;
    float sq2 = sqrtf(fmaxf(b2_ * b2_ - 16.0f * c2, 0.0f));
    float r2 = (b2_ + sq2) / 2.0f;
    float a3 = 4.0f * ov;
    float b3 = -2.0f * ov * (hh + ww);
    float c3 = (ov - 1.0f) * ww * hh;
    float sq3 = sqrtf(fmaxf(b3 * b3 - 4.0f * a3 * c3, 0.0f));
    float r3 = (b3 + sq3) / 2.0f;
    float r = fminf(fminf(r1, r2), r3);
    r = fmaxf(floorf(r), 2.0f);
    float sigma = (2.0f * r + 1.0f) / 6.0f;
    float inv2s2 = 1.0f / (2.0f * sigma * sigma);
    bool valid = (dx > 0.0f) && (dy > 0.0f);
    float vf = valid ? 1.0f : 0.0f;
    vals[0] = (cx - cxf) * vf;
    vals[1] = (cy - cyf) * vf;
    vals[2] = z * vf;
    vals[3] = logf(dx) * vf;
    vals[4] = logf(dy) * vf;
    vals[5] = logf(dz) * vf;
    vals[6] = cosf(hd) * vf;
    vals[7] = sinf(hd) * vf;
    indf = (float)((cyi * HWD + cxi) * (valid ? 1 : 0));
    mkf = vf;
    float* bp = boxp + (b * MBOX + j) * 8;
    bp[0] = cxf; bp[1] = cyf; bp[2] = r; bp[3] = inv2s2;
    bp[4] = valid ? cls : 0.0f; bp[5] = 0.f; bp[6] = 0.f; bp[7] = 0.f;
  }
  float* tb = out + TB_OFF + (b * NMAX + j) * 8;
#pragma unroll
  for (int k = 0; k < 8; ++k) tb[k] = vals[k];
  out[IND_OFF + b * NMAX + j] = indf;
  out[MSK_OFF + b * NMAX + j] = mkf;
}

// ---------------- heatmap: per-pixel max over boxes ----------------
__global__ __launch_bounds__(256) void heatmap_kernel(
    const float* __restrict__ boxp, float* __restrict__ out) {
  __shared__ float s_bp[MBOX][5];
  const int t = threadIdx.x, b = blockIdx.y;
  for (int e = t; e < MBOX * 5; e += 256) {
    int j = e / 5, k = e - j * 5;
    s_bp[j][k] = boxp[(b * MBOX + j) * 8 + k];
  }
  __syncthreads();
  int p = blockIdx.x * 256 + t;
  if (p >= NPX) return;
  int y = p / HWD, x = p - y * HWD;
  float a0 = 0.f, a1 = 0.f, a2 = 0.f;
  for (int j = 0; j < MBOX; ++j) {
    int c = (int)s_bp[j][4];
    if (c == 0) continue;
    float ox = (float)x - s_bp[j][0];
    float oy = (float)y - s_bp[j][1];
    float r = s_bp[j][2];
    if (fabsf(ox) <= r && fabsf(oy) <= r) {
      float gg = expf(-(ox * ox + oy * oy) * s_bp[j][3]);
      if (c == 1) a0 = fmaxf(a0, gg);
      else if (c == 2) a1 = fmaxf(a1, gg);
      else a2 = fmaxf(a2, gg);
    }
  }
  int base = HM_OFF + (b * 3 * HWD + y) * HWD + x;
  out[base] = a0;
  out[base + NPX] = a1;
  out[base + 2 * NPX] = a2;
}

extern "C" void kernel_launch(void* const* d_in, const int* in_sizes, int n_in,
                              void* d_out, int out_size, void* d_ws, size_t ws_size,
                              hipStream_t stream) {
  (void)in_sizes; (void)n_in; (void)out_size;
  const float* sf = (const float*)d_in[0];
  const float* gt = (const float*)d_in[1];
  const float* w_shared = (const float*)d_in[2];
  const float* bn_shared = (const float*)d_in[3];
  const float* w1 = (const float*)d_in[4];
  const float* bnH = (const float*)d_in[5];
  const float* w2 = (const float*)d_in[6];
  const float* b2 = (const float*)d_in[7];
  float* out = (float*)d_out;
  char* ws = (char*)d_ws;

  // ws layout (bytes)
  const size_t SH = (size_t)NB * NPX * 64 * 2;          // 18,096,128
  unsigned short* shared_t = (unsigned short*)ws;
  unsigned short* w1b = (unsigned short*)(ws + SH);                       // 589,824
  unsigned short* w2b = (unsigned short*)(ws + SH + 589824);              // 442,368
  unsigned short* w3b = (unsigned short*)(ws + SH + 589824 + 442368);     // 110,592
  float* boxp = (float*)(ws + SH + 589824 + 442368 + 110592);             // 25,600
  const size_t off_tmp = SH + 589824 + 442368 + 110592 + 25600;           // 19,264,512
  unsigned short* tmp0 = (unsigned short*)(ws + off_tmp);

  const bool wide = ws_size >= off_tmp + 6 * SH;                 // ~128 MB
  const long long tstride = wide ? (long long)(SH / 2) : 0LL;    // shorts

  wprep<<<2232, 256, 0, stream>>>(w_shared, w1, w2, w1b, w2b, w3b);

  conv1_mfma<<<dim3(144, NB), 512, 0, stream>>>(sf, w1b, bn_shared, shared_t);

  if (wide) {
    conv_head_mfma<4, 0><<<dim3(144, NB, 6), 256, 0, stream>>>(
        shared_t, w2b, bnH, nullptr, tmp0, nullptr, 0, tstride);
    conv_head_mfma<1, 1><<<dim3(144, NB, 6), 256, 0, stream>>>(
        tmp0, w3b, nullptr, b2, nullptr, out, 0, tstride);
  } else {
    for (int h = 0; h < 6; ++h) {
      conv_head_mfma<4, 0><<<dim3(144, NB), 256, 0, stream>>>(
          shared_t, w2b, bnH, nullptr, tmp0, nullptr, h, 0);
      conv_head_mfma<1, 1><<<dim3(144, NB), 256, 0, stream>>>(
          tmp0, w3b, nullptr, b2, nullptr, out, h, 0);
    }
  }

  targets_kernel<<<(NB * NMAX + 255) / 256, 256, 0, stream>>>(gt, out, boxp);
  heatmap_kernel<<<dim3((NPX + 255) / 256, NB), 256, 0, stream>>>(boxp, out);
}